// Round 7
// baseline (695.021 us; speedup 1.0000x reference)
//
#include <hip/hip_runtime.h>

// fTN_NNiso: batched PEPS amplitude, MI355X. TWO-PASS:
//  pass 1 gen_q : q[s][51200] = h_s @ W2 + b2  (bf16 into d_ws; chunked if ws small)
//  pass 2 tn_con: boundary-MPS sweep, G=2 samples/block, 256 threads:
//    waves 0-1 = phases (one wave per sample, round-6 validated bodies),
//    waves 2-3 = staging (issue global loads during phases, write LDS after
//    the phase barrier -> single-buffered P/Q/A2, live regs tiny).
// Rounds 4-6 lesson: allocator pins 128 VGPR on the 512-thread shape and
// spills (WRITE_SIZE 73-90MB). This shape keeps every path's live set <120.
// peps strides (6,6,4,4,4,4,2): r:3072 c:512 l:128 rb:32 a:8 b:2 p:1

constexpr int   kNSites = 36;
constexpr int   kProj   = 51200;
constexpr float kEta    = 0.001f;
constexpr int   G       = 2;

__device__ __forceinline__ float4 f4fma(float s, float4 a, float4 c) {
    c.x = fmaf(s, a.x, c.x); c.y = fmaf(s, a.y, c.y);
    c.z = fmaf(s, a.z, c.z); c.w = fmaf(s, a.w, c.w);
    return c;
}
__device__ __forceinline__ unsigned short f2bf(float f) {
    union { float f; unsigned int u; } v; v.f = f;
    unsigned int r = v.u + 0x7FFFu + ((v.u >> 16) & 1u);  // RNE
    return (unsigned short)(r >> 16);
}
__device__ __forceinline__ float bf2f(unsigned int h) {
    union { unsigned int u; float f; } v; v.u = h << 16;
    return v.f;
}

// ===================== PASS 1: q = h @ W2 + b2 (bf16) =====================
__global__ __launch_bounds__(256)
void gen_q(const int* __restrict__ x,
           const float* __restrict__ W1,
           const float* __restrict__ b1,
           const float* __restrict__ W2,
           const float* __restrict__ b2,
           unsigned short* __restrict__ qout,
           int s0, int send)
{
    __shared__ float hT[64 * 64];   // [k*64 + sl]
    __shared__ uint2 xb[64];        // 36-bit occupation mask per sample
    const int tid   = threadIdx.x;
    const int sbase = s0 + blockIdx.x * 64;
    const int ns    = blockIdx.y;   // 200 strips of 256 cols

    if (tid < 64) {
        int s = sbase + tid; if (s >= send) s = send - 1;
        unsigned int m0 = 0, m1 = 0;
        for (int j = 0; j < 32; ++j) m0 |= ((unsigned int)x[s * kNSites + j] & 1u) << j;
        for (int j = 32; j < 36; ++j) m1 |= ((unsigned int)x[s * kNSites + j] & 1u) << (j - 32);
        xb[tid] = make_uint2(m0, m1);
    }
    __syncthreads();
    for (int i = tid; i < 4096; i += 256) {
        int k = i >> 6, sl = i & 63;
        uint2 m = xb[sl];
        float a = b1[k];
#pragma unroll
        for (int j = 0; j < 32; ++j)
            a += ((m.x >> j) & 1u) ? W1[j * 64 + k] : 0.0f;
#pragma unroll
        for (int j = 0; j < 4; ++j)
            a += ((m.y >> j) & 1u) ? W1[(32 + j) * 64 + k] : 0.0f;
        hT[k * 64 + sl] = fmaxf(a, 0.0f);
    }
    __syncthreads();

    const int sgrp = tid >> 6;            // wave-uniform
    const int c4   = (tid & 63) * 4;
    const int col  = ns * 256 + c4;
    float4 acc[16];
#pragma unroll
    for (int i = 0; i < 16; ++i) acc[i] = make_float4(0, 0, 0, 0);
    const float* wp = W2 + col;
#pragma unroll 8
    for (int k = 0; k < 64; ++k) {
        float4 w = *reinterpret_cast<const float4*>(wp + (size_t)k * kProj);
#pragma unroll
        for (int s4 = 0; s4 < 4; ++s4) {
            float4 hv = *reinterpret_cast<const float4*>(&hT[k * 64 + sgrp * 16 + s4 * 4]);
            acc[s4 * 4 + 0] = f4fma(hv.x, w, acc[s4 * 4 + 0]);
            acc[s4 * 4 + 1] = f4fma(hv.y, w, acc[s4 * 4 + 1]);
            acc[s4 * 4 + 2] = f4fma(hv.z, w, acc[s4 * 4 + 2]);
            acc[s4 * 4 + 3] = f4fma(hv.w, w, acc[s4 * 4 + 3]);
        }
    }
    float4 bb = *reinterpret_cast<const float4*>(b2 + col);
#pragma unroll
    for (int i = 0; i < 16; ++i) {
        int s = sbase + sgrp * 16 + i;
        if (s < send) {
            ushort4 uv;
            uv.x = f2bf(acc[i].x + bb.x); uv.y = f2bf(acc[i].y + bb.y);
            uv.z = f2bf(acc[i].z + bb.z); uv.w = f2bf(acc[i].w + bb.w);
            *reinterpret_cast<ushort4*>(qout + (size_t)(s - s0) * kProj + col) = uv;
        }
    }
}

// ===================== PASS 2: contraction sweep =====================
// LDS layout (float offsets), G=2
constexpr int OFF_MS  = 0;         // [g][r-1][d][(u*4+l)^((d&7)<<2)]   2*4096
constexpr int OFF_MS0 = 8192;      // [g][d*4+l]                        2*64
constexpr int OFF_MS5 = 8320;      // [g][u*4+l]                        2*64
constexpr int OFF_P   = 8448;      // [g][d*64+b*16+cc]                 2*1024
constexpr int OFF_Q   = 10496;     // [g][cq*68+ua]                     2*1088
constexpr int OFF_M2  = 12672;     // [g][ua*32+(colh^((ua>>2&7)<<2))]  2*2048
constexpr int OFF_A2  = 16768;     // [g][lb*16+a*4+rb]                 2*256
constexpr int OFF_VB  = 17280;     // [g][16]                           32
constexpr int LTOT    = 17312;     // 69,248 B

__global__ __launch_bounds__(256, 2)
void tn_con(const int* __restrict__ x,
            const float* __restrict__ peps,
            const float* __restrict__ base_proj,
            const unsigned short* __restrict__ qc,
            float* __restrict__ out,
            int s0, int send)
{
    __shared__ __align__(16) float L[LTOT];
    __shared__ int xl[G * kNSites];

    const int tid   = threadIdx.x;
    const int wid   = tid >> 6;
    const int lane  = tid & 63;
    const int sBase = s0 + blockIdx.x * G;

    // ---- stage x ----
    if (tid < G * kNSites) {
        int g = tid / kNSites, ii = tid - g * kNSites;
        int s = sBase + g; if (s >= send) s = send - 1;
        xl[tid] = x[s * kNSites + ii];
    }
    for (int i = tid; i < 8448; i += 256) L[i] = 0.0f;  // Ms + Ms0 + Ms5
    __syncthreads();

    // ---- init boundary MPS from column 0 ----
    for (int idx = tid; idx < 1024; idx += 256) {
        int g = idx >> 9, rem = idx & 511;
        int rr = rem >> 6, u = (rem >> 4) & 3, d = (rem >> 2) & 3, l = rem & 3;
        if (rr >= 6) continue;
        int p = xl[g * kNSites + rr * 6];
        if (rr == 0) {
            if (u == 0) L[OFF_MS0 + g * 64 + d * 4 + l] = peps[l * 32 + d * 2 + p];
        } else if (rr == 5) {
            if (d == 0) L[OFF_MS5 + g * 64 + u * 4 + l] = peps[5 * 3072 + l * 32 + u * 8 + p];
        } else {
            L[OFF_MS + g * 4096 + (rr - 1) * 1024 + d * 64 + ((u * 4 + l) ^ ((d & 7) << 2))] =
                peps[rr * 3072 + l * 32 + u * 8 + d * 2 + p];
        }
    }
    __syncthreads();

    // ---- stage-wave persistent context ----
    const int t   = tid - 128;            // stage lane 0..127 (wid>=2)
    const int sg  = (t >> 6) & 1;         // staged sample
    const int k16 = t & 63;               // 16-elem chunk within a bond half
    int sAbs = sBase + sg; if (sAbs >= send) sAbs = send - 1;
    const unsigned short* qcs = qc + (size_t)(sAbs - s0) * kProj;
    uint4 heldQ0 = make_uint4(0,0,0,0), heldQ1 = make_uint4(0,0,0,0);

    // ---- prologue: stage bond 0 (P now, hold Q) + A2(site 0 = c1,r0) ----
    if (wid >= 2) {
        const int go = k16 * 16;  // bond 0 base
        uint4 p0 = *reinterpret_cast<const uint4*>(qcs + go);
        uint4 p1 = *reinterpret_cast<const uint4*>(qcs + go + 8);
        heldQ0 = *reinterpret_cast<const uint4*>(qcs + 1024 + go);
        heldQ1 = *reinterpret_cast<const uint4*>(qcs + 1024 + go + 8);
        const float* bp = base_proj + go;
        const int dst = OFF_P + sg * 1024 + k16 * 16;
        unsigned int qw[4] = {p0.x, p0.y, p0.z, p0.w};
        unsigned int qv[4] = {p1.x, p1.y, p1.z, p1.w};
#pragma unroll
        for (int h = 0; h < 2; ++h) {
            unsigned int* qq = h ? qv : qw;
#pragma unroll
            for (int i = 0; i < 2; ++i) {
                float4 b = *reinterpret_cast<const float4*>(bp + h * 8 + i * 4);
                float4 o;
                o.x = b.x + kEta * bf2f(qq[i*2]   & 0xffffu);
                o.y = b.y + kEta * bf2f(qq[i*2]   >> 16);
                o.z = b.z + kEta * bf2f(qq[i*2+1] & 0xffffu);
                o.w = b.w + kEta * bf2f(qq[i*2+1] >> 16);
                *reinterpret_cast<float4*>(&L[dst + h * 8 + i * 4]) = o;
            }
        }
        // A2 for site 0 (c=1, r=0): adim=1, bdim=4, rdim=4
#pragma unroll
        for (int j = 0; j < 4; ++j) {
            int idx = t + j * 128;
            int g2 = idx >> 8, rest = idx & 255;
            int lb = rest >> 4, arb = rest & 15;
            int l = lb >> 2, b = lb & 3, a = arb >> 2, rb = arb & 3;
            float v = 0.0f;
            if (a < 1) {
                int p = xl[g2 * kNSites + 0 * 6 + 1];
                v = peps[1 * 512 + l * 128 + rb * 32 + a * 8 + b * 2 + p];
            }
            L[OFF_A2 + idx] = v;
        }
    }
    __syncthreads();

    // ---- site loop: s = (c-1)*6 + r, 30 sites ----
    int s = 0;
    for (int c = 1; c < 6; ++c) {
        for (int r = 0; r < 6; ++r, ++s) {
            if (wid < 2) {
                // ================= PHASES (sample g = wid) =================
                const int g   = wid;
                const int Pb  = OFF_P  + g * 1024;
                const int Qb  = OFF_Q  + g * 1088;
                const int M2b = OFF_M2 + g * 2048;
                const int A2b = OFF_A2 + g * 256;

                if (r == 0) {
                    const int cc = lane >> 2, rb = lane & 3;
                    float mold0[16];
#pragma unroll
                    for (int i = 0; i < 16; ++i) mold0[i] = 0.0f;
#pragma unroll
                    for (int d = 0; d < 16; ++d) {
                        float4 ms = *reinterpret_cast<float4*>(&L[OFF_MS0 + g*64 + d*4]);
                        float msl[4] = {ms.x, ms.y, ms.z, ms.w};
#pragma unroll
                        for (int b = 0; b < 4; ++b) {
                            float pv = L[Pb + d*64 + b*16 + cc];
#pragma unroll
                            for (int l = 0; l < 4; ++l)
                                mold0[l*4+b] = fmaf(msl[l], pv, mold0[l*4+b]);
                        }
                    }
                    float o = 0.0f;
#pragma unroll
                    for (int lb = 0; lb < 16; ++lb)
                        o = fmaf(mold0[lb], L[A2b + lb*16 + rb], o);
                    L[OFF_MS0 + g*64 + cc*4 + rb] = o;
                } else if (r < 5) {
                    const int u = lane & 15, ccq = lane >> 4;
                    const int msr = OFF_MS + g*4096 + (r-1)*1024;
                    float4 acc[16];
#pragma unroll
                    for (int i = 0; i < 16; ++i) acc[i] = make_float4(0,0,0,0);
#pragma unroll
                    for (int b = 0; b < 4; ++b) {
                        asm volatile("" ::: "memory");   // keep per-b reads (reg pressure)
                        float4 mold[4] = {make_float4(0,0,0,0), make_float4(0,0,0,0),
                                          make_float4(0,0,0,0), make_float4(0,0,0,0)};
#pragma unroll
                        for (int d = 0; d < 16; ++d) {
                            const int wsz = (d & 7) << 2;
                            float4 ms = *reinterpret_cast<float4*>(&L[msr + d*64 + ((u*4) ^ wsz)]);
                            float4 p  = *reinterpret_cast<float4*>(&L[Pb + d*64 + b*16 + ccq*4]);
                            mold[0] = f4fma(ms.x, p, mold[0]);
                            mold[1] = f4fma(ms.y, p, mold[1]);
                            mold[2] = f4fma(ms.z, p, mold[2]);
                            mold[3] = f4fma(ms.w, p, mold[3]);
                        }
#pragma unroll
                        for (int l = 0; l < 4; ++l) {
                            float ml[4] = {mold[l].x, mold[l].y, mold[l].z, mold[l].w};
#pragma unroll
                            for (int a = 0; a < 4; ++a) {
                                float4 av = *reinterpret_cast<float4*>(&L[A2b + (l*4+b)*16 + a*4]);
#pragma unroll
                                for (int cco = 0; cco < 4; ++cco)
                                    acc[a*4+cco] = f4fma(ml[cco], av, acc[a*4+cco]);
                            }
                        }
                    }
                    // 2-pass: write M2 half, p3 (Q @ M2) half
                    const int cq0 = (lane >> 3) * 2, colg = lane & 7, colh0 = colg * 4;
#pragma unroll
                    for (int ph = 0; ph < 2; ++ph) {
                        if ((ccq >> 1) == ph) {
#pragma unroll
                            for (int a = 0; a < 4; ++a) {
                                const int ua = u*4 + a;
                                const int wsz = (u & 7) << 2;
#pragma unroll
                                for (int cco = 0; cco < 4; ++cco) {
                                    int colh = (ccq & 1) * 16 + cco * 4;
                                    *reinterpret_cast<float4*>(&L[M2b + ua*32 + (colh ^ wsz)]) = acc[a*4+cco];
                                }
                            }
                        }
                        float4 o0 = make_float4(0,0,0,0), o1 = make_float4(0,0,0,0);
#pragma unroll
                        for (int ua0 = 0; ua0 < 64; ua0 += 4) {
                            float4 q0 = *reinterpret_cast<float4*>(&L[Qb + cq0*68 + ua0]);
                            float4 q1 = *reinterpret_cast<float4*>(&L[Qb + (cq0+1)*68 + ua0]);
                            const int wsz = ((ua0 >> 2) & 7) << 2;
                            float4 m0 = *reinterpret_cast<float4*>(&L[M2b + (ua0+0)*32 + (colh0 ^ wsz)]);
                            float4 m1 = *reinterpret_cast<float4*>(&L[M2b + (ua0+1)*32 + (colh0 ^ wsz)]);
                            float4 m2 = *reinterpret_cast<float4*>(&L[M2b + (ua0+2)*32 + (colh0 ^ wsz)]);
                            float4 m3 = *reinterpret_cast<float4*>(&L[M2b + (ua0+3)*32 + (colh0 ^ wsz)]);
                            o0 = f4fma(q0.x, m0, o0); o0 = f4fma(q0.y, m1, o0);
                            o0 = f4fma(q0.z, m2, o0); o0 = f4fma(q0.w, m3, o0);
                            o1 = f4fma(q1.x, m0, o1); o1 = f4fma(q1.y, m1, o1);
                            o1 = f4fma(q1.z, m2, o1); o1 = f4fma(q1.w, m3, o1);
                        }
                        const int dn = ph * 8 + colg;
                        const int wsd = (dn & 7) << 2;
                        *reinterpret_cast<float4*>(&L[msr + dn*64 + ((cq0*4) ^ wsd)]) = o0;
                        *reinterpret_cast<float4*>(&L[msr + dn*64 + (((cq0+1)*4) ^ wsd)]) = o1;
                    }
                } else { // r == 5
                    {
                        const int u5 = lane >> 2, a5 = lane & 3;
                        float4 ms5 = *reinterpret_cast<float4*>(&L[OFF_MS5 + g*64 + u5*4]);
                        float m5l[4] = {ms5.x, ms5.y, ms5.z, ms5.w};
                        float4 o = make_float4(0,0,0,0);
#pragma unroll
                        for (int l = 0; l < 4; ++l) {
                            float4 av = *reinterpret_cast<float4*>(&L[A2b + (l*4)*16 + a5*4]);
                            o = f4fma(m5l[l], av, o);
                        }
                        *reinterpret_cast<float4*>(&L[M2b + lane*4]) = o;
                    }
                    {
                        const int cq = lane >> 2, rb = lane & 3;
                        float o = 0.0f;
#pragma unroll
                        for (int ua0 = 0; ua0 < 64; ua0 += 4) {
                            float4 q = *reinterpret_cast<float4*>(&L[Qb + cq*68 + ua0]);
                            o = fmaf(q.x, L[M2b + (ua0+0)*4 + rb], o);
                            o = fmaf(q.y, L[M2b + (ua0+1)*4 + rb], o);
                            o = fmaf(q.z, L[M2b + (ua0+2)*4 + rb], o);
                            o = fmaf(q.w, L[M2b + (ua0+3)*4 + rb], o);
                        }
                        L[OFF_MS5 + g*64 + cq*4 + rb] = o;
                    }
                }
                __syncthreads();   // phases done
                __syncthreads();   // stage writes done
            } else {
                // ================= STAGE (waves 2-3) =================
                // issue loads (overlap with phases) for bond sigma=s+1 and A2(site s+1)
                uint4 iP0 = make_uint4(0,0,0,0), iP1 = iP0, iQ0 = iP0, iQ1 = iP0;
                float a2v[4] = {0,0,0,0};
                const int s1 = s + 1;
                const bool haveNext = (s1 <= 29);
                const bool haveBond = haveNext && (s1 % 6 <= 4);
                int mP = 0;
                if (haveBond) {
                    mP = 5 * (s1 / 6) + (s1 % 6);
                    const int go = mP * 2048 + k16 * 16;
                    iP0 = *reinterpret_cast<const uint4*>(qcs + go);
                    iP1 = *reinterpret_cast<const uint4*>(qcs + go + 8);
                    iQ0 = *reinterpret_cast<const uint4*>(qcs + go + 1024);
                    iQ1 = *reinterpret_cast<const uint4*>(qcs + go + 1024 + 8);
                }
                if (haveNext) {
                    const int r1 = s1 % 6, c1 = 1 + s1 / 6;
                    const int adim = (r1 == 0) ? 1 : 4;
                    const int bdim = (r1 == 5) ? 1 : 4;
                    const int rdim = (c1 == 5) ? 1 : 4;
#pragma unroll
                    for (int j = 0; j < 4; ++j) {
                        int idx = t + j * 128;
                        int g2 = idx >> 8, rest = idx & 255;
                        int lb = rest >> 4, arb = rest & 15;
                        int l = lb >> 2, b = lb & 3, a = arb >> 2, rb = arb & 3;
                        float v = 0.0f;
                        if (a < adim && b < bdim && rb < rdim) {
                            int p = xl[g2 * kNSites + r1 * 6 + c1];
                            v = peps[r1 * 3072 + c1 * 512 + l * 128 + rb * 32 + a * 8 + b * 2 + p];
                        }
                        a2v[j] = v;
                    }
                }
                __syncthreads();   // phases done -> safe to write buffers
                if (haveBond) {    // P <- bond mP
                    const int go = mP * 2048 + k16 * 16;
                    const float* bp = base_proj + go;
                    const int dst = OFF_P + sg * 1024 + k16 * 16;
                    unsigned int qw[4] = {iP0.x, iP0.y, iP0.z, iP0.w};
                    unsigned int qv[4] = {iP1.x, iP1.y, iP1.z, iP1.w};
#pragma unroll
                    for (int h = 0; h < 2; ++h) {
                        unsigned int* qq = h ? qv : qw;
#pragma unroll
                        for (int i = 0; i < 2; ++i) {
                            float4 b = *reinterpret_cast<const float4*>(bp + h * 8 + i * 4);
                            float4 o;
                            o.x = b.x + kEta * bf2f(qq[i*2]   & 0xffffu);
                            o.y = b.y + kEta * bf2f(qq[i*2]   >> 16);
                            o.z = b.z + kEta * bf2f(qq[i*2+1] & 0xffffu);
                            o.w = b.w + kEta * bf2f(qq[i*2+1] >> 16);
                            *reinterpret_cast<float4*>(&L[dst + h * 8 + i * 4]) = o;
                        }
                    }
                }
                if ((s % 6 <= 4) && s <= 28) {  // Q <- bond sigma=s (held)
                    const int mQ = 5 * (s / 6) + (s % 6);
                    const int go = mQ * 2048 + 1024 + k16 * 16;
                    const float* bp = base_proj + go;
                    const int dst = OFF_Q + sg * 1088 + (k16 >> 2) * 68 + (k16 & 3) * 16;
                    unsigned int qw[4] = {heldQ0.x, heldQ0.y, heldQ0.z, heldQ0.w};
                    unsigned int qv[4] = {heldQ1.x, heldQ1.y, heldQ1.z, heldQ1.w};
#pragma unroll
                    for (int h = 0; h < 2; ++h) {
                        unsigned int* qq = h ? qv : qw;
#pragma unroll
                        for (int i = 0; i < 2; ++i) {
                            float4 b = *reinterpret_cast<const float4*>(bp + h * 8 + i * 4);
                            float4 o;
                            o.x = b.x + kEta * bf2f(qq[i*2]   & 0xffffu);
                            o.y = b.y + kEta * bf2f(qq[i*2]   >> 16);
                            o.z = b.z + kEta * bf2f(qq[i*2+1] & 0xffffu);
                            o.w = b.w + kEta * bf2f(qq[i*2+1] >> 16);
                            *reinterpret_cast<float4*>(&L[dst + h * 8 + i * 4]) = o;
                        }
                    }
                }
                heldQ0 = iQ0; heldQ1 = iQ1;
                if (haveNext) {
#pragma unroll
                    for (int j = 0; j < 4; ++j)
                        L[OFF_A2 + t + j * 128] = a2v[j];
                }
                __syncthreads();   // stage writes done
            }
        }
    }

    // ---- final chain contraction (rb = 0 after c=5) ----
    if (wid < 2) {
        const int g = wid;
        if (lane < 16) L[OFF_VB + g*16 + lane] = L[OFF_MS0 + g*64 + lane*4];
        for (int rr = 1; rr < 5; ++rr) {
            float a = 0.0f;
            if (lane < 16) {
#pragma unroll
                for (int u = 0; u < 16; ++u)
                    a = fmaf(L[OFF_VB + g*16 + u],
                             L[OFF_MS + g*4096 + (rr-1)*1024 + lane*64 + ((u*4) ^ ((lane&7)<<2))], a);
            }
            if (lane < 16) L[OFF_VB + g*16 + lane] = a;
        }
        if (lane == 0 && sBase + g < send) {
            float a = 0.0f;
#pragma unroll
            for (int u = 0; u < 16; ++u)
                a = fmaf(L[OFF_VB + g*16 + u], L[OFF_MS5 + g*64 + u*4], a);
            out[sBase + g] = a;
        }
    }
}

extern "C" void kernel_launch(void* const* d_in, const int* in_sizes, int n_in,
                              void* d_out, int out_size, void* d_ws, size_t ws_size,
                              hipStream_t stream) {
    const int*   x         = (const int*)d_in[0];
    const float* peps      = (const float*)d_in[1];
    const float* base_proj = (const float*)d_in[2];
    const float* W1        = (const float*)d_in[3];
    const float* b1        = (const float*)d_in[4];
    const float* W2        = (const float*)d_in[5];
    const float* b2        = (const float*)d_in[6];
    float*       out       = (float*)d_out;

    const int batch = in_sizes[0] / kNSites;
    const size_t perS = (size_t)kProj * 2;  // bf16 bytes per sample
    int cs = (int)(ws_size / perS);
    if (cs > batch) cs = batch;
    cs &= ~3;
    if (cs < 4) cs = 4;  // requires ws_size >= 409600 B

    for (int s0 = 0; s0 < batch; s0 += cs) {
        int send = s0 + cs; if (send > batch) send = batch;
        int n = send - s0;
        dim3 g1((n + 63) / 64, 200);
        hipLaunchKernelGGL(gen_q, g1, dim3(256), 0, stream,
                           x, W1, b1, W2, b2, (unsigned short*)d_ws, s0, send);
        hipLaunchKernelGGL(tn_con, dim3((n + G - 1) / G), dim3(256), 0, stream,
                           x, peps, base_proj, (const unsigned short*)d_ws, out, s0, send);
    }
}